// Round 9
// baseline (115.991 us; speedup 1.0000x reference)
//
#include <hip/hip_runtime.h>

// ConvQuadInterp3d: 3x3x3 replicate-padded stencil, quadratic peak refinement.
// Input  x: FP32, (2,1,10,512,512)
// Output: FP32, coords_max (2,1,3,10,512,512) ++ y_max (2,1,10,512,512)
//   Round-8 deduction: output dtype is fp32. The bf16-output hypothesis was
//   falsified by the round-7 write-only probe (absmax 512.0 is impossible for
//   any coords layout under bf16 reads); under fp32 reads, every round 0-8
//   result (incl. both probes) is explained exactly: my earlier ushort writes
//   covered only half the fp32 buffer, leaving memset-zeros vs ref=512.
// Coords channel order: jax source order ch0=d+dx2, ch1=h+dx1, ch2=w+dx0.
// Internal math fp32. One thread computes 4 consecutive w outputs.
//
// NaN discipline: fast-math-safe by construction — keep = |num| <= 0.7*|det|
// evaluated WITHOUT dividing; 1/det only taken when keep (=> det != 0); no
// inf/NaN ever exists in a register.

constexpr int Dd = 10, Hh = 512, Ww = 512;
constexpr int HW  = Hh * Ww;        // 262144
constexpr int DHW = Dd * HW;        // 2621440
constexpr float BONUS_F = 10.0f;

__global__ __launch_bounds__(256) void quad_kernel(
        const float* __restrict__ x, float* __restrict__ out) {
    const int tx = threadIdx.x;                 // 0..127
    const int w0 = tx << 2;                     // 4 outputs per thread
    const int h  = (blockIdx.y << 1) + threadIdx.y;
    const int bd = blockIdx.z;                  // 0..19: plane index (b*Dd + d)
    const int d  = bd % Dd;
    const int b  = bd / Dd;

    const int pz[3] = { (d == 0) ? bd : bd - 1, bd, (d == Dd - 1) ? bd : bd + 1 };
    const int py[3] = { (h == 0) ? h : h - 1, h, (h == Hh - 1) ? h : h + 1 };
    const int wl = (w0 == 0) ? 0 : w0 - 1;
    const int wr = (w0 + 4 >= Ww) ? (Ww - 1) : (w0 + 4);

    // v[zz][yy][k]: k=0..5 maps to w = w0-1 .. w0+4 (clamped at volume faces)
    float v[3][3][6];
#pragma unroll
    for (int zz = 0; zz < 3; ++zz) {
#pragma unroll
        for (int yy = 0; yy < 3; ++yy) {
            const float* rp = x + (size_t)pz[zz] * HW + (size_t)py[yy] * Ww;
            const float4 c = *reinterpret_cast<const float4*>(rp + w0);  // 16B aligned
            v[zz][yy][0] = rp[wl];
            v[zz][yy][1] = c.x;
            v[zz][yy][2] = c.y;
            v[zz][yy][3] = c.z;
            v[zz][yy][4] = c.w;
            v[zz][yy][5] = rp[wr];
        }
    }

    float o_d[4], o_h[4], o_w[4], o_y[4];
#pragma unroll
    for (int j = 0; j < 4; ++j) {
        const int k = j + 1;
        const float xc = v[1][1][k];

        // nmax = max(26 neighbors, 0); replicate padding at faces puts the
        // center itself into the neighbor set -> m is false there (matches ref).
        float nm = 0.0f;
#pragma unroll
        for (int zz = 0; zz < 3; ++zz)
#pragma unroll
            for (int yy = 0; yy < 3; ++yy)
#pragma unroll
                for (int dw = -1; dw <= 1; ++dw) {
                    if (zz == 1 && yy == 1 && dw == 0) continue;
                    nm = fmaxf(nm, v[zz][yy][k + dw]);
                }
        const bool m = xc > nm;

        const float gx  = 0.5f * (v[1][1][k + 1] - v[1][1][k - 1]);
        const float gy  = 0.5f * (v[1][2][k] - v[1][0][k]);
        const float gs  = 0.5f * (v[2][1][k] - v[0][1][k]);
        const float dxx = v[1][1][k - 1] + v[1][1][k + 1] - 2.0f * xc;
        const float dyy = v[1][0][k] + v[1][2][k] - 2.0f * xc;
        const float dss = v[0][1][k] + v[2][1][k] - 2.0f * xc;
        const float dxy = 0.25f * (v[1][0][k - 1] + v[1][2][k + 1] - v[1][2][k - 1] - v[1][0][k + 1]);
        const float dys = 0.25f * (v[0][0][k] + v[2][2][k] - v[2][0][k] - v[0][2][k]);
        const float dxs = 0.25f * (v[0][1][k - 1] + v[2][1][k + 1] - v[2][1][k - 1] - v[0][1][k + 1]);

        // Cramer numerators of H*s = g. Rm eps (<=1e-7) dropped: kept dx differ
        // by O(eps); near-singular dets rejected by keep, like ref's far>0.7.
        const float c00 = dyy * dss - dys * dys;
        const float c01 = dxy * dss - dys * dxs;
        const float c02 = dxy * dys - dyy * dxs;
        const float det = dxx * c00 - dxy * c01 + dxs * c02;
        const float t1  = gy * dss - dys * gs;
        const float t2  = gy * dys - dyy * gs;
        const float t3  = dxy * gs - gy * dxs;
        const float nx = gx * c00 - dxy * t1 + dxs * t2;            // sx * det
        const float ny = dxx * t1 - gx * c01 + dxs * t3;            // sy * det
        const float ns = dxx * (-t2) - dxy * t3 + gx * c02;         // ss * det

        // keep <=> m && det!=0 && all |num/det| <= 0.7, WITHOUT dividing.
        const float lim = 0.7f * fabsf(det);
        const bool keep = m && (fabsf(det) > 0.0f) &&
                          (fabsf(nx) <= lim) && (fabsf(ny) <= lim) && (fabsf(ns) <= lim);
        const float rdet = keep ? (1.0f / det) : 0.0f;
        const float dx0 = -nx * rdet;                   // keep ? -nx/det : 0  (finite)
        const float dx1 = -ny * rdet;
        const float dx2 = -ns * rdet;

        const float dy_ = 0.5f * (gx * dx0 + gy * dx1 + gs * dx2);
        const float y   = xc + dy_ + (m ? BONUS_F : 0.0f);

        o_d[j] = (float)d + dx2;
        o_h[j] = (float)h + dx1;
        o_w[j] = (float)(w0 + j) + dx0;
        o_y[j] = y;
    }

    const size_t base = (size_t)d * HW + (size_t)h * Ww + w0;
    auto pack = [](const float* s) { return make_float4(s[0], s[1], s[2], s[3]); };
    // coords_max (B,1,3,D,H,W): ch0 = d+dx2, ch1 = h+dx1, ch2 = w+dx0 (jax order)
    *reinterpret_cast<float4*>(out + ((size_t)(b * 3 + 0)) * DHW + base) = pack(o_d);
    *reinterpret_cast<float4*>(out + ((size_t)(b * 3 + 1)) * DHW + base) = pack(o_h);
    *reinterpret_cast<float4*>(out + ((size_t)(b * 3 + 2)) * DHW + base) = pack(o_w);
    // y_max after coords: offset 2*3*DHW
    *reinterpret_cast<float4*>(out + (size_t)6 * DHW + (size_t)b * DHW + base) = pack(o_y);
}

extern "C" void kernel_launch(void* const* d_in, const int* in_sizes, int n_in,
                              void* d_out, int out_size, void* d_ws, size_t ws_size,
                              hipStream_t stream) {
    (void)in_sizes; (void)n_in; (void)out_size; (void)d_ws; (void)ws_size;
    const float* x = (const float*)d_in[0];
    float* out = (float*)d_out;
    dim3 block(128, 2, 1);
    dim3 grid(1, Hh / 2, 2 * Dd);   // (w-strip, H/2 rows, B*D planes)
    quad_kernel<<<grid, block, 0, stream>>>(x, out);
}